// Round 3
// baseline (249.407 us; speedup 1.0000x reference)
//
#include <hip/hip_runtime.h>
#include <hip/hip_bf16.h>

typedef unsigned short u16;
typedef __bf16 bf16_8 __attribute__((ext_vector_type(8)));
typedef float f32_4 __attribute__((ext_vector_type(4)));

#define IN_DIM 512
#define HID 64
#define OUT_DIM 40
#define CAP 64        // CSR slot capacity; deg~Poisson(16), P(deg>63)~0, guarded
#define CF_BLOCKS 512 // countfill partition size in k_work (64 blocks x 8 XCD slices)

// ---- prep: zero cnt + transpose W1 fp32[512][64] -> W1t bf16[64][512] ----
__global__ void k_prep(const float* __restrict__ W1, u16* __restrict__ W1t,
                       int* __restrict__ cnt, int n) {
    int i = blockIdx.x * 256 + threadIdx.x;
    if (i < n) cnt[i] = 0;
    if (i < IN_DIM * HID) {
        int k = i / HID, o = i % HID;
        __hip_bfloat16 v = __float2bfloat16(W1[i]);
        W1t[o * IN_DIM + k] = *reinterpret_cast<u16*>(&v);
    }
}

// ---- fused work: blocks [0,NT) = GEMM tiles; blocks [NT, NT+CF_BLOCKS) = count+fill ----
// GEMM (latency-bound on X loads) and countfill (scatter-bound) are independent; running
// them concurrently hides countfill under gemm. hs is stored UNSCALED (cnt is being
// concurrently updated; dinv scaling happens in k_scale).
// R1 post-mortem: the LDS double-buffer + explicit x0/x1 prefetch IS the software
// pipeline — removing it regressed 80->117 us. Keep this structure.
// R2 post-mortem: WRITE_SIZE 53MB ~= csr(6.4MB) x 8 XCDs — non-coherent per-XCD L2s each
// dirty nearly every 64B sector of csr (scattered 2B writes from all XCDs), 8x RFO+WB
// amplification ~= 100MB random-sector HBM traffic. Fix: XCD-local dst slices — CF block's
// XCD is blockIdx.x & 7 (round-robin dispatch); each slice's 64 blocks scan all edges
// (coalesced, L3-hot) and process only dst in-slice, so csr writes stay in one L2.
// Mapping is a perf heuristic only — correctness holds for any block->XCD assignment.
__launch_bounds__(256)
__global__ void k_work(const float* __restrict__ X, const u16* __restrict__ W1t,
                       const int* __restrict__ src, const int* __restrict__ dst,
                       int* cnt, u16* __restrict__ csr, u16* __restrict__ hs,
                       int N, int E, int NT) {
    __shared__ __align__(16) u16 As[2][64 * 40];
    const int t = threadIdx.x;

    if ((int)blockIdx.x >= NT) {
        // ---------------- countfill partition (XCD-sliced) ----------------
        const int slice = (int)blockIdx.x & 7;            // XCD id under round-robin
        const int rank  = ((int)blockIdx.x - NT) >> 3;    // 0..63 within slice
        const int lo = (int)(((long)slice * N) >> 3);
        const int hi = (int)(((long)(slice + 1) * N) >> 3);
        const int stride = 64 * 256;
        int e = rank * 256 + t;
        for (; e + 3 * stride < E; e += 4 * stride) {
            int d0 = dst[e];
            int d1 = dst[e + stride];
            int d2 = dst[e + 2 * stride];
            int d3 = dst[e + 3 * stride];
            if (d0 >= lo && d0 < hi) {
                int p = atomicAdd(&cnt[d0], 1);
                if (p < CAP) csr[(size_t)d0 * CAP + p] = (u16)src[e];
            }
            if (d1 >= lo && d1 < hi) {
                int p = atomicAdd(&cnt[d1], 1);
                if (p < CAP) csr[(size_t)d1 * CAP + p] = (u16)src[e + stride];
            }
            if (d2 >= lo && d2 < hi) {
                int p = atomicAdd(&cnt[d2], 1);
                if (p < CAP) csr[(size_t)d2 * CAP + p] = (u16)src[e + 2 * stride];
            }
            if (d3 >= lo && d3 < hi) {
                int p = atomicAdd(&cnt[d3], 1);
                if (p < CAP) csr[(size_t)d3 * CAP + p] = (u16)src[e + 3 * stride];
            }
        }
        for (; e < E; e += stride) {
            int d = dst[e];
            if (d >= lo && d < hi) {
                int p = atomicAdd(&cnt[d], 1);
                if (p < CAP) csr[(size_t)d * CAP + p] = (u16)src[e];
            }
        }
        return;
    }

    // ---------------- GEMM tile: hs(bf16) = X @ W1 (unscaled) ----------------
    const int wave = t >> 6;
    const int lane = t & 63;
    const int m = lane & 15;
    const int quad = lane >> 4;
    const int n0 = blockIdx.x * 64;

    f32_4 acc[4];
    #pragma unroll
    for (int c = 0; c < 4; c++) acc[c] = (f32_4){0.f, 0.f, 0.f, 0.f};

    const int r_st = t >> 2;        // 0..63
    const int k_st = (t & 3) * 8;   // 0,8,16,24

    int row = n0 + r_st; if (row >= N) row = N - 1;
    const float* xp = X + (size_t)row * IN_DIM + k_st;

    f32_4 x0 = *reinterpret_cast<const f32_4*>(xp);
    f32_4 x1 = *reinterpret_cast<const f32_4*>(xp + 4);

    int buf = 0;
    for (int k0 = 0; k0 < IN_DIM; k0 += 32) {
        u16 xb[8];
        #pragma unroll
        for (int q = 0; q < 4; q++) {
            __hip_bfloat16 c0 = __float2bfloat16(x0[q]);
            __hip_bfloat16 c1 = __float2bfloat16(x1[q]);
            xb[q]     = *reinterpret_cast<u16*>(&c0);
            xb[4 + q] = *reinterpret_cast<u16*>(&c1);
        }
        *reinterpret_cast<uint4*>(&As[buf][r_st * 40 + k_st]) = *reinterpret_cast<uint4*>(xb);
        __syncthreads();

        if (k0 + 32 < IN_DIM) {
            x0 = *reinterpret_cast<const f32_4*>(xp + k0 + 32);
            x1 = *reinterpret_cast<const f32_4*>(xp + k0 + 36);
        }

        bf16_8 a = *reinterpret_cast<const bf16_8*>(&As[buf][(wave * 16 + m) * 40 + quad * 8]);
        #pragma unroll
        for (int c = 0; c < 4; c++) {    // B fragment from global W1t (64 KB, L2-hot)
            bf16_8 b = *reinterpret_cast<const bf16_8*>(
                W1t + (size_t)(c * 16 + m) * IN_DIM + k0 + quad * 8);
            acc[c] = __builtin_amdgcn_mfma_f32_16x16x32_bf16(a, b, acc[c], 0, 0, 0);
        }
        buf ^= 1;
    }

    // C layout: col = lane&15 (=m), row = quad*4 + reg. Store UNSCALED.
    const int nbase = n0 + wave * 16 + quad * 4;
    #pragma unroll
    for (int r = 0; r < 4; r++) {
        int n = nbase + r;
        if (n < N) {
            #pragma unroll
            for (int c = 0; c < 4; c++) {
                __hip_bfloat16 hv = __float2bfloat16(acc[c][r]);
                hs[(size_t)n * HID + c * 16 + m] = *reinterpret_cast<u16*>(&hv);
            }
        }
    }
}

// ---- scale pass: hs[n] = bf16(dinv[n] * hs[n]) in place (cnt is final now) ----
__global__ void k_scale(u16* __restrict__ hs, const int* __restrict__ cnt, int N) {
    int i = blockIdx.x * 256 + threadIdx.x;
    int node = i >> 3;
    if (node >= N) return;
    float dv = rsqrtf((float)cnt[node] + 1.0f);
    uint4 v = *reinterpret_cast<uint4*>(hs + (size_t)i * 8);
    uint vv[4] = {v.x, v.y, v.z, v.w};
    u16 o[8];
    #pragma unroll
    for (int q = 0; q < 4; q++) {
        float lo = __uint_as_float(vv[q] << 16) * dv;
        float hi = __uint_as_float(vv[q] & 0xFFFF0000u) * dv;
        __hip_bfloat16 bl_ = __float2bfloat16(lo);
        __hip_bfloat16 bh_ = __float2bfloat16(hi);
        o[2 * q]     = *reinterpret_cast<u16*>(&bl_);
        o[2 * q + 1] = *reinterpret_cast<u16*>(&bh_);
    }
    *reinterpret_cast<uint4*>(hs + (size_t)i * 8) = *reinterpret_cast<uint4*>(o);
}

// ---- fused agg + ReLU + FC(MFMA) ----
// hs rows are PRE-SCALED by dinv[s]; only the outer dinv[n] remains.
// CSR row (64 entries = 128B) is loaded cooperatively (uint2 per lane) and
// redistributed via __shfl. Aggregation runs in masked 16-deep gather rounds:
// deg~Poisson(16) means most nodes finish in ONE dependent-latency round
// (indices clamped to N-1; out-of-deg lanes' values zeroed — adding 0.0 is exact).
__device__ __forceinline__ void acc_add(f32_4& a, uint2 v) {
    a[0] += __uint_as_float(v.x << 16);
    a[1] += __uint_as_float(v.x & 0xFFFF0000u);
    a[2] += __uint_as_float(v.y << 16);
    a[3] += __uint_as_float(v.y & 0xFFFF0000u);
}

#define SHP 72   // padded row pitch (bf16 elems): 144 B, conflict-free for b128 reads

__launch_bounds__(256)
__global__ void k_aggfc(const u16* __restrict__ hs, const u16* __restrict__ csr,
                        const int* __restrict__ cnt, const float* __restrict__ b1,
                        const float* __restrict__ Wfc, const float* __restrict__ bfc,
                        float* __restrict__ out, int N) {
    __shared__ __align__(16) u16 shb[16 * SHP];   // h2 rows, bf16, A-operand layout
    __shared__ __align__(16) u16 wfb[48 * SHP];   // Wfc^T padded: [o][k], rows 40..47 = 0
    __shared__ float bl[48];
    const int t = threadIdx.x;

    for (int i = t; i < 48 * HID; i += 256) {
        int o = i / HID, k = i % HID;
        float v = (o < OUT_DIM) ? Wfc[o * HID + k] : 0.f;
        __hip_bfloat16 b = __float2bfloat16(v);
        wfb[o * SHP + k] = *reinterpret_cast<u16*>(&b);
    }
    if (t < 48) bl[t] = (t < OUT_DIM) ? bfc[t] : 0.f;

    const int g = t >> 4, l = t & 15;
    const int n = blockIdx.x * 16 + g;

    if (n < N) {
        const uint2* hs2 = reinterpret_cast<const uint2*>(hs);
        f32_4 aa[4];
        #pragma unroll
        for (int q = 0; q < 4; q++) aa[q] = (f32_4){0.f, 0.f, 0.f, 0.f};
        const float dvn = rsqrtf((float)cnt[n] + 1.0f);
        acc_add(aa[0], hs2[(size_t)n * 16 + l]);         // self loop (pre-scaled)
        int deg = cnt[n]; if (deg > CAP) deg = CAP;
        // lane l holds CSR entries 4l..4l+3 of this node's row
        uint2 cv = reinterpret_cast<const uint2*>(csr + (size_t)n * CAP)[l];
        const int nn1 = N - 1;
        for (int j = 0; j < deg; j += 16) {
            int base = j >> 2;
            uint wx[4], wy[4];
            #pragma unroll
            for (int q = 0; q < 4; q++) {
                wx[q] = __shfl(cv.x, base + q, 16);
                wy[q] = __shfl(cv.y, base + q, 16);
            }
            int s[16];
            #pragma unroll
            for (int q = 0; q < 4; q++) {
                s[4 * q + 0] = (int)(wx[q] & 0xffff);
                s[4 * q + 1] = (int)(wx[q] >> 16);
                s[4 * q + 2] = (int)(wy[q] & 0xffff);
                s[4 * q + 3] = (int)(wy[q] >> 16);
            }
            uint2 v[16];
            #pragma unroll
            for (int i = 0; i < 16; i++) {
                int si = s[i] < nn1 ? s[i] : nn1;        // clamp (garbage-slot safety)
                v[i] = hs2[(size_t)si * 16 + l];
            }
            #pragma unroll
            for (int i = 0; i < 16; i++) {
                if (j + i >= deg) { v[i].x = 0u; v[i].y = 0u; }
                acc_add(aa[i & 3], v[i]);
            }
        }
        f32_4 acc = (aa[0] + aa[1]) + (aa[2] + aa[3]);
        u16 rb[4];
        #pragma unroll
        for (int q = 0; q < 4; q++) {
            float x = dvn * acc[q] + b1[l * 4 + q];
            x = x > 0.f ? x : 0.f;                       // ReLU
            __hip_bfloat16 hb = __float2bfloat16(x);
            rb[q] = *reinterpret_cast<u16*>(&hb);
        }
        *reinterpret_cast<uint2*>(&shb[g * SHP + l * 4]) = *reinterpret_cast<uint2*>(rb);
    }
    __syncthreads();

    // FC via MFMA: wave w handles o-tile w (w<3)
    const int wave = t >> 6;
    const int lane = t & 63;
    const int m = lane & 15;
    const int quad = lane >> 4;
    if (wave < 3) {
        bf16_8 a0 = *reinterpret_cast<const bf16_8*>(&shb[m * SHP + quad * 8]);
        bf16_8 a1 = *reinterpret_cast<const bf16_8*>(&shb[m * SHP + 32 + quad * 8]);
        bf16_8 b0 = *reinterpret_cast<const bf16_8*>(&wfb[(wave * 16 + m) * SHP + quad * 8]);
        bf16_8 b1 = *reinterpret_cast<const bf16_8*>(&wfb[(wave * 16 + m) * SHP + 32 + quad * 8]);
        f32_4 c = (f32_4){0.f, 0.f, 0.f, 0.f};
        c = __builtin_amdgcn_mfma_f32_16x16x32_bf16(a0, b0, c, 0, 0, 0);
        c = __builtin_amdgcn_mfma_f32_16x16x32_bf16(a1, b1, c, 0, 0, 0);
        const int o = wave * 16 + m;
        if (o < OUT_DIM) {
            const int base = blockIdx.x * 16;
            #pragma unroll
            for (int r = 0; r < 4; r++) {
                int node = base + quad * 4 + r;
                if (node < N) out[(size_t)node * OUT_DIM + o] = c[r] + bl[o];
            }
        }
    }
}

// ---------------- launch ----------------

extern "C" void kernel_launch(void* const* d_in, const int* in_sizes, int n_in,
                              void* d_out, int out_size, void* d_ws, size_t ws_size,
                              hipStream_t stream) {
    const float* X   = (const float*)d_in[0];
    const int* edges = (const int*)d_in[1];
    const float* W1  = (const float*)d_in[2];
    const float* b1  = (const float*)d_in[3];
    const float* Wfc = (const float*)d_in[4];
    const float* bfc = (const float*)d_in[5];

    const int N = in_sizes[0] / IN_DIM;
    const int E = in_sizes[1] / 2;
    const int* src = edges;
    const int* dst = edges + E;

    char* p = (char*)d_ws;
    auto carve = [&](size_t bytes) -> char* {
        char* r = p;
        p += (bytes + 255) & ~(size_t)255;
        return r;
    };
    u16* W1t = (u16*)carve((size_t)IN_DIM * HID * 2);
    u16* hs  = (u16*)carve((size_t)N * HID * 2);
    int* cnt = (int*)carve((size_t)N * 4);
    u16* csr = (u16*)carve((size_t)N * CAP * 2);

    const int nb = (N + 255) / 256;
    const int NT = (N + 63) / 64;

    k_prep <<<nb, 256, 0, stream>>>(W1, W1t, cnt, N);
    k_work <<<NT + CF_BLOCKS, 256, 0, stream>>>(X, W1t, src, dst, cnt, csr, hs, N, E, NT);
    k_scale<<<(N * 8 + 255) / 256, 256, 0, stream>>>(hs, cnt, N);
    k_aggfc<<<(N + 15) / 16, 256, 0, stream>>>(hs, csr, cnt, b1, Wfc, bfc,
                                               (float*)d_out, N);
}

// Round 4
// 233.301 us; speedup vs baseline: 1.0690x; 1.0690x over previous
//
#include <hip/hip_runtime.h>
#include <hip/hip_bf16.h>

typedef unsigned short u16;
typedef __bf16 bf16_8 __attribute__((ext_vector_type(8)));
typedef float f32_4 __attribute__((ext_vector_type(4)));

#define IN_DIM 512
#define HID 64
#define OUT_DIM 40
#define CAP 64        // CSR slot capacity; deg~Poisson(16), P(deg>63)~0, guarded
#define CF_BLOCKS 512 // countfill partition size in k_work

// ---- prep: zero cnt + transpose W1 fp32[512][64] -> W1t bf16[64][512] ----
__global__ void k_prep(const float* __restrict__ W1, u16* __restrict__ W1t,
                       int* __restrict__ cnt, int n) {
    int i = blockIdx.x * 256 + threadIdx.x;
    if (i < n) cnt[i] = 0;
    if (i < IN_DIM * HID) {
        int k = i / HID, o = i % HID;
        __hip_bfloat16 v = __float2bfloat16(W1[i]);
        W1t[o * IN_DIM + k] = *reinterpret_cast<u16*>(&v);
    }
}

// ---- fused work: blocks [0,NT) = GEMM tiles; blocks [NT, NT+CF_BLOCKS) = count+fill ----
// R1 post-mortem: LDS double-buffer + register prefetch IS the pipeline scaffold; keep.
// R3 post-mortem: controlled experiment (CF work x8 -> k_work +17us) shows CF runs in the
// GEMM's tail; the GEMM partition itself is the ~80us pole. GEMM is barrier-drain-bound:
// hipcc emits s_waitcnt vmcnt(0) before every s_barrier, so register prefetch is drained
// at each of the 32 barriers/block. R4 change: BK=64 — 8 K-steps instead of 16, halving
// the drain count and doubling bytes-in-flight per drain. LDS 2x64x72x2B = 36KB -> 4
// blocks/CU (~= measured 3.4 occupancy, not a regression).
// R3 also: XCD-sliced CF reverted — write-amp mechanism confirmed (WRITE 53->37) but the
// 8x dst re-scan cost more than the locality won.
__launch_bounds__(256)
__global__ void k_work(const float* __restrict__ X, const u16* __restrict__ W1t,
                       const int* __restrict__ src, const int* __restrict__ dst,
                       int* cnt, u16* __restrict__ csr, u16* __restrict__ hs,
                       int N, int E, int NT) {
    __shared__ __align__(16) u16 As[2][64 * 72];
    const int t = threadIdx.x;

    if ((int)blockIdx.x >= NT) {
        // ---------------- countfill partition ----------------
        int tid = ((int)blockIdx.x - NT) * 256 + t;
        int stride = CF_BLOCKS * 256;
        for (int e = tid; e < E; e += stride) {
            int d = dst[e];
            int p = atomicAdd(&cnt[d], 1);
            if (p < CAP) csr[(size_t)d * CAP + p] = (u16)src[e];
        }
        return;
    }

    // ---------------- GEMM tile: hs(bf16) = X @ W1 (unscaled), BK=64 ----------------
    const int wave = t >> 6;
    const int lane = t & 63;
    const int m = lane & 15;
    const int quad = lane >> 4;
    const int n0 = blockIdx.x * 64;

    f32_4 acc[4];
    #pragma unroll
    for (int c = 0; c < 4; c++) acc[c] = (f32_4){0.f, 0.f, 0.f, 0.f};

    const int r_st = t >> 2;        // 0..63: staged row
    const int c2 = t & 3;           // 16-float chunk within the 64-k step

    int row = n0 + r_st; if (row >= N) row = N - 1;
    const float* xp = X + (size_t)row * IN_DIM + c2 * 16;

    f32_4 x0 = *reinterpret_cast<const f32_4*>(xp);
    f32_4 x1 = *reinterpret_cast<const f32_4*>(xp + 4);
    f32_4 x2 = *reinterpret_cast<const f32_4*>(xp + 8);
    f32_4 x3 = *reinterpret_cast<const f32_4*>(xp + 12);

    int buf = 0;
    for (int k0 = 0; k0 < IN_DIM; k0 += 64) {
        // convert 16 floats -> bf16 and stage (row pitch 72: conflict-free b128)
        u16 xb[16];
        #pragma unroll
        for (int q = 0; q < 4; q++) {
            __hip_bfloat16 c0 = __float2bfloat16(x0[q]);
            __hip_bfloat16 c1 = __float2bfloat16(x1[q]);
            __hip_bfloat16 c2_ = __float2bfloat16(x2[q]);
            __hip_bfloat16 c3 = __float2bfloat16(x3[q]);
            xb[q]      = *reinterpret_cast<u16*>(&c0);
            xb[4 + q]  = *reinterpret_cast<u16*>(&c1);
            xb[8 + q]  = *reinterpret_cast<u16*>(&c2_);
            xb[12 + q] = *reinterpret_cast<u16*>(&c3);
        }
        u16* wp = &As[buf][r_st * 72 + c2 * 16];
        *reinterpret_cast<uint4*>(wp)     = *reinterpret_cast<uint4*>(&xb[0]);
        *reinterpret_cast<uint4*>(wp + 8) = *reinterpret_cast<uint4*>(&xb[8]);
        __syncthreads();

        if (k0 + 64 < IN_DIM) {     // register prefetch of next 64-k step
            x0 = *reinterpret_cast<const f32_4*>(xp + k0 + 64);
            x1 = *reinterpret_cast<const f32_4*>(xp + k0 + 68);
            x2 = *reinterpret_cast<const f32_4*>(xp + k0 + 72);
            x3 = *reinterpret_cast<const f32_4*>(xp + k0 + 76);
        }

        bf16_8 a0 = *reinterpret_cast<const bf16_8*>(&As[buf][(wave * 16 + m) * 72 + quad * 8]);
        bf16_8 a1 = *reinterpret_cast<const bf16_8*>(&As[buf][(wave * 16 + m) * 72 + 32 + quad * 8]);
        #pragma unroll
        for (int c = 0; c < 4; c++) {    // B fragments from global W1t (64 KB, L2-hot)
            bf16_8 b0 = *reinterpret_cast<const bf16_8*>(
                W1t + (size_t)(c * 16 + m) * IN_DIM + k0 + quad * 8);
            bf16_8 b1 = *reinterpret_cast<const bf16_8*>(
                W1t + (size_t)(c * 16 + m) * IN_DIM + k0 + 32 + quad * 8);
            acc[c] = __builtin_amdgcn_mfma_f32_16x16x32_bf16(a0, b0, acc[c], 0, 0, 0);
            acc[c] = __builtin_amdgcn_mfma_f32_16x16x32_bf16(a1, b1, acc[c], 0, 0, 0);
        }
        __syncthreads();
        buf ^= 1;
    }

    // C layout: col = lane&15 (=m), row = quad*4 + reg. Store UNSCALED.
    const int nbase = n0 + wave * 16 + quad * 4;
    #pragma unroll
    for (int r = 0; r < 4; r++) {
        int n = nbase + r;
        if (n < N) {
            #pragma unroll
            for (int c = 0; c < 4; c++) {
                __hip_bfloat16 hv = __float2bfloat16(acc[c][r]);
                hs[(size_t)n * HID + c * 16 + m] = *reinterpret_cast<u16*>(&hv);
            }
        }
    }
}

// ---- scale pass: hs[n] = bf16(dinv[n] * hs[n]) in place (cnt is final now) ----
__global__ void k_scale(u16* __restrict__ hs, const int* __restrict__ cnt, int N) {
    int i = blockIdx.x * 256 + threadIdx.x;
    int node = i >> 3;
    if (node >= N) return;
    float dv = rsqrtf((float)cnt[node] + 1.0f);
    uint4 v = *reinterpret_cast<uint4*>(hs + (size_t)i * 8);
    uint vv[4] = {v.x, v.y, v.z, v.w};
    u16 o[8];
    #pragma unroll
    for (int q = 0; q < 4; q++) {
        float lo = __uint_as_float(vv[q] << 16) * dv;
        float hi = __uint_as_float(vv[q] & 0xFFFF0000u) * dv;
        __hip_bfloat16 bl_ = __float2bfloat16(lo);
        __hip_bfloat16 bh_ = __float2bfloat16(hi);
        o[2 * q]     = *reinterpret_cast<u16*>(&bl_);
        o[2 * q + 1] = *reinterpret_cast<u16*>(&bh_);
    }
    *reinterpret_cast<uint4*>(hs + (size_t)i * 8) = *reinterpret_cast<uint4*>(o);
}

// ---- fused agg + ReLU + FC(MFMA) ----
// hs rows are PRE-SCALED by dinv[s]; only the outer dinv[n] remains.
// CSR row loaded cooperatively (uint2 per lane), redistributed via __shfl;
// masked 16-deep gather rounds (R3: measured neutral vs 8-deep — keep, stop tuning).
__device__ __forceinline__ void acc_add(f32_4& a, uint2 v) {
    a[0] += __uint_as_float(v.x << 16);
    a[1] += __uint_as_float(v.x & 0xFFFF0000u);
    a[2] += __uint_as_float(v.y << 16);
    a[3] += __uint_as_float(v.y & 0xFFFF0000u);
}

#define SHP 72   // padded row pitch (bf16 elems): 144 B, conflict-free for b128 reads

__launch_bounds__(256)
__global__ void k_aggfc(const u16* __restrict__ hs, const u16* __restrict__ csr,
                        const int* __restrict__ cnt, const float* __restrict__ b1,
                        const float* __restrict__ Wfc, const float* __restrict__ bfc,
                        float* __restrict__ out, int N) {
    __shared__ __align__(16) u16 shb[16 * SHP];   // h2 rows, bf16, A-operand layout
    __shared__ __align__(16) u16 wfb[48 * SHP];   // Wfc^T padded: [o][k], rows 40..47 = 0
    __shared__ float bl[48];
    const int t = threadIdx.x;

    for (int i = t; i < 48 * HID; i += 256) {
        int o = i / HID, k = i % HID;
        float v = (o < OUT_DIM) ? Wfc[o * HID + k] : 0.f;
        __hip_bfloat16 b = __float2bfloat16(v);
        wfb[o * SHP + k] = *reinterpret_cast<u16*>(&b);
    }
    if (t < 48) bl[t] = (t < OUT_DIM) ? bfc[t] : 0.f;

    const int g = t >> 4, l = t & 15;
    const int n = blockIdx.x * 16 + g;

    if (n < N) {
        const uint2* hs2 = reinterpret_cast<const uint2*>(hs);
        f32_4 aa[4];
        #pragma unroll
        for (int q = 0; q < 4; q++) aa[q] = (f32_4){0.f, 0.f, 0.f, 0.f};
        const float dvn = rsqrtf((float)cnt[n] + 1.0f);
        acc_add(aa[0], hs2[(size_t)n * 16 + l]);         // self loop (pre-scaled)
        int deg = cnt[n]; if (deg > CAP) deg = CAP;
        // lane l holds CSR entries 4l..4l+3 of this node's row
        uint2 cv = reinterpret_cast<const uint2*>(csr + (size_t)n * CAP)[l];
        const int nn1 = N - 1;
        for (int j = 0; j < deg; j += 16) {
            int base = j >> 2;
            uint wx[4], wy[4];
            #pragma unroll
            for (int q = 0; q < 4; q++) {
                wx[q] = __shfl(cv.x, base + q, 16);
                wy[q] = __shfl(cv.y, base + q, 16);
            }
            int s[16];
            #pragma unroll
            for (int q = 0; q < 4; q++) {
                s[4 * q + 0] = (int)(wx[q] & 0xffff);
                s[4 * q + 1] = (int)(wx[q] >> 16);
                s[4 * q + 2] = (int)(wy[q] & 0xffff);
                s[4 * q + 3] = (int)(wy[q] >> 16);
            }
            uint2 v[16];
            #pragma unroll
            for (int i = 0; i < 16; i++) {
                int si = s[i] < nn1 ? s[i] : nn1;        // clamp (garbage-slot safety)
                v[i] = hs2[(size_t)si * 16 + l];
            }
            #pragma unroll
            for (int i = 0; i < 16; i++) {
                if (j + i >= deg) { v[i].x = 0u; v[i].y = 0u; }
                acc_add(aa[i & 3], v[i]);
            }
        }
        f32_4 acc = (aa[0] + aa[1]) + (aa[2] + aa[3]);
        u16 rb[4];
        #pragma unroll
        for (int q = 0; q < 4; q++) {
            float x = dvn * acc[q] + b1[l * 4 + q];
            x = x > 0.f ? x : 0.f;                       // ReLU
            __hip_bfloat16 hb = __float2bfloat16(x);
            rb[q] = *reinterpret_cast<u16*>(&hb);
        }
        *reinterpret_cast<uint2*>(&shb[g * SHP + l * 4]) = *reinterpret_cast<uint2*>(rb);
    }
    __syncthreads();

    // FC via MFMA: wave w handles o-tile w (w<3)
    const int wave = t >> 6;
    const int lane = t & 63;
    const int m = lane & 15;
    const int quad = lane >> 4;
    if (wave < 3) {
        bf16_8 a0 = *reinterpret_cast<const bf16_8*>(&shb[m * SHP + quad * 8]);
        bf16_8 a1 = *reinterpret_cast<const bf16_8*>(&shb[m * SHP + 32 + quad * 8]);
        bf16_8 b0 = *reinterpret_cast<const bf16_8*>(&wfb[(wave * 16 + m) * SHP + quad * 8]);
        bf16_8 b1 = *reinterpret_cast<const bf16_8*>(&wfb[(wave * 16 + m) * SHP + 32 + quad * 8]);
        f32_4 c = (f32_4){0.f, 0.f, 0.f, 0.f};
        c = __builtin_amdgcn_mfma_f32_16x16x32_bf16(a0, b0, c, 0, 0, 0);
        c = __builtin_amdgcn_mfma_f32_16x16x32_bf16(a1, b1, c, 0, 0, 0);
        const int o = wave * 16 + m;
        if (o < OUT_DIM) {
            const int base = blockIdx.x * 16;
            #pragma unroll
            for (int r = 0; r < 4; r++) {
                int node = base + quad * 4 + r;
                if (node < N) out[(size_t)node * OUT_DIM + o] = c[r] + bl[o];
            }
        }
    }
}

// ---------------- launch ----------------

extern "C" void kernel_launch(void* const* d_in, const int* in_sizes, int n_in,
                              void* d_out, int out_size, void* d_ws, size_t ws_size,
                              hipStream_t stream) {
    const float* X   = (const float*)d_in[0];
    const int* edges = (const int*)d_in[1];
    const float* W1  = (const float*)d_in[2];
    const float* b1  = (const float*)d_in[3];
    const float* Wfc = (const float*)d_in[4];
    const float* bfc = (const float*)d_in[5];

    const int N = in_sizes[0] / IN_DIM;
    const int E = in_sizes[1] / 2;
    const int* src = edges;
    const int* dst = edges + E;

    char* p = (char*)d_ws;
    auto carve = [&](size_t bytes) -> char* {
        char* r = p;
        p += (bytes + 255) & ~(size_t)255;
        return r;
    };
    u16* W1t = (u16*)carve((size_t)IN_DIM * HID * 2);
    u16* hs  = (u16*)carve((size_t)N * HID * 2);
    int* cnt = (int*)carve((size_t)N * 4);
    u16* csr = (u16*)carve((size_t)N * CAP * 2);

    const int nb = (N + 255) / 256;
    const int NT = (N + 63) / 64;

    k_prep <<<nb, 256, 0, stream>>>(W1, W1t, cnt, N);
    k_work <<<NT + CF_BLOCKS, 256, 0, stream>>>(X, W1t, src, dst, cnt, csr, hs, N, E, NT);
    k_scale<<<(N * 8 + 255) / 256, 256, 0, stream>>>(hs, cnt, N);
    k_aggfc<<<(N + 15) / 16, 256, 0, stream>>>(hs, csr, cnt, b1, Wfc, bfc,
                                               (float*)d_out, N);
}